// Round 3
// baseline (141.890 us; speedup 1.0000x reference)
//
#include <hip/hip_runtime.h>

#define TPB 512
#define NBLOCKS 1024   // 4 blocks/CU x 256 CU; 4 x 8 waves = 32 waves/CU = 100%
#define REPL 16        // 16-way pair-table replication -> 32 KB LDS

__device__ __forceinline__ float fade_f(float t) {
    // 6t^5 - 15t^4 + 10t^3 (Horner, fmaf)
    return t * t * t * fmaf(t, fmaf(t, 6.0f, -15.0f), 10.0f);
}

__device__ __forceinline__ float lerp_f(float a, float b, float t) {
    return fmaf(t, b - a, a);
}

// Leaf word w: gi = perm % 12 in bits 0..3 (bits 4..6 zero), perm<<7 above.
// grad3 rows: 0..3 = (±1,±1,0), 4..7 = (±1,0,±1), 8..11 = (0,±1,±1)
// c1 = gi<8 ? dx : dy ; c2 = gi<4 ? dy : dz ; signs = bit0, bit1.
__device__ __forceinline__ float gdot_w(unsigned w, float dx, float dy, float dz) {
    unsigned gi = w & 0xFu;
    float c1 = (gi < 8u) ? dx : dy;
    float c2 = (gi < 4u) ? dy : dz;
    unsigned s1 = w << 31;                    // bit0 -> sign of c1
    unsigned s2 = (w << 30) & 0x80000000u;    // bit1 -> sign of c2
    return __uint_as_float(__float_as_uint(c1) ^ s1)
         + __uint_as_float(__float_as_uint(c2) ^ s2);
}

__global__ __launch_bounds__(TPB, 8) void perlin_kernel(
    const float* __restrict__ xg, const float* __restrict__ yg,
    const float* __restrict__ zg, const int* __restrict__ perm,
    float* __restrict__ out, int nquads)
{
    // Pair table: P[i*REPL + c] = { w(i), w((i+1)&255) },
    // w(j) = (perm[j]<<7) | (perm[j]%12).
    // Every hash level needs entries (t, t+1) -> one ds_read_b64 per pair.
    // Banking: entry i, copy c lives at words 64*i + {2c, 2c+1} -> banks
    // {2c, 2c+1} independent of i. 4 lanes/copy * 2 words = 4 words/bank =
    // the wave64 b64 floor: zero bank conflicts by construction.
    __shared__ uint2 P[256 * REPL];  // 32 KB

    for (int s = threadIdx.x; s < 256 * REPL; s += TPB) {
        int i = s >> 4;
        unsigned p0 = (unsigned)perm[i];
        unsigned p1 = (unsigned)perm[(i + 1) & 255];
        P[s] = make_uint2((p0 << 7) | (p0 % 12u), (p1 << 7) | (p1 % 12u));
    }
    __syncthreads();

    const char* Tl = (const char*)P + ((threadIdx.x & (REPL - 1)) << 3);

    const float4* x4 = (const float4*)xg;
    const float4* y4 = (const float4*)yg;
    const float4* z4 = (const float4*)zg;
    float4* o4 = (float4*)out;

    const int stride = gridDim.x * TPB;
    for (int q = blockIdx.x * TPB + threadIdx.x; q < nquads; q += stride) {
        float4 xv = x4[q], yv = y4[q], zv = z4[q];
        float xa[4] = {xv.x, xv.y, xv.z, xv.w};
        float ya[4] = {yv.x, yv.y, yv.z, yv.w};
        float za[4] = {zv.x, zv.y, zv.z, zv.w};
        float4 res;
        float* rp = &res.x;

        #pragma unroll
        for (int e = 0; e < 4; ++e) {
            float X = xa[e], Y = ya[e], Z = za[e];
            float fx = floorf(X), fy = floorf(Y), fz = floorf(Z);
            float xf = X - fx, yf = Y - fy, zf = Z - fz;
            // lattice coords pre-scaled to the 128-byte entry stride
            unsigned x7 = (unsigned)(int)fx << 7;
            unsigned y7 = (unsigned)(int)fy << 7;
            unsigned z7 = (unsigned)(int)fz << 7;
            float u = fade_f(xf), v = fade_f(yf), w = fade_f(zf);
            float xf1 = xf - 1.0f, yf1 = yf - 1.0f, zf1 = zf - 1.0f;

            // hash tree: 1 + 2 + 4 paired lookups (b64 each)
            #define LK(t) (*(const uint2*)(Tl + ((t) & 0x7F80u)))
            uint2 lv1 = LK(x7);               // {A, B}
            uint2 p_a = LK(lv1.x + y7);       // {aa, ab}
            uint2 p_b = LK(lv1.y + y7);       // {ba, bb}
            uint2 paa = LK(p_a.x + z7);       // {waaa, waab}
            uint2 pab = LK(p_a.y + z7);       // {waba, wabb}
            uint2 pba = LK(p_b.x + z7);       // {wbaa, wbab}
            uint2 pbb = LK(p_b.y + z7);       // {wbba, wbbb}
            #undef LK

            float g_aaa = gdot_w(paa.x, xf,  yf,  zf);
            float g_aab = gdot_w(paa.y, xf,  yf,  zf1);
            float g_aba = gdot_w(pab.x, xf,  yf1, zf);
            float g_abb = gdot_w(pab.y, xf,  yf1, zf1);
            float g_baa = gdot_w(pba.x, xf1, yf,  zf);
            float g_bab = gdot_w(pba.y, xf1, yf,  zf1);
            float g_bba = gdot_w(pbb.x, xf1, yf1, zf);
            float g_bbb = gdot_w(pbb.y, xf1, yf1, zf1);

            float l1 = lerp_f(g_aaa, g_baa, u);
            float l2 = lerp_f(g_aba, g_bba, u);
            float l3 = lerp_f(g_aab, g_bab, u);
            float l4 = lerp_f(g_abb, g_bbb, u);
            float m1 = lerp_f(l1, l2, v);
            float m2 = lerp_f(l3, l4, v);
            rp[e] = lerp_f(m1, m2, w);
        }
        o4[q] = res;
    }
}

extern "C" void kernel_launch(void* const* d_in, const int* in_sizes, int n_in,
                              void* d_out, int out_size, void* d_ws, size_t ws_size,
                              hipStream_t stream) {
    const float* x   = (const float*)d_in[0];
    const float* y   = (const float*)d_in[1];
    const float* z   = (const float*)d_in[2];
    const int* perm  = (const int*)d_in[3];
    // d_in[4] (grad3) unused: gradients derived arithmetically from the index
    float* out = (float*)d_out;
    int nquads = out_size >> 2;  // 32*512*512 divisible by 4
    perlin_kernel<<<NBLOCKS, TPB, 0, stream>>>(x, y, z, perm, out, nquads);
}